// Round 1
// baseline (2330.147 us; speedup 1.0000x reference)
//
#include <hip/hip_runtime.h>
#include <hip/hip_bf16.h>

#define B_ 32
#define T_ 2000
#define S_ 400
#define C0_ 80
#define H_ 256

static constexpr float NEGV = -1e9f;
static constexpr int NMU  = B_ * T_ * S_;       // 25,600,000
static constexpr int NPI  = 2 * NMU;            // 51,200,000
static constexpr int NWSP = B_ * T_ * H_;       // 16,384,000

// ---------------- conv1d (K=5, SAME) + bias + tanh ----------------------
// y[b,t,co] = tanh(bias[co] + sum_{k,ci} x[b,t+k-2,ci] * w[k,ci,co])
template<int CIN>
__global__ __launch_bounds__(256)
void conv1d_tanh(const float* __restrict__ x, const float* __restrict__ w,
                 const float* __restrict__ bias, float* __restrict__ y)
{
  constexpr int TT  = 32;        // t rows per block
  constexpr int JW  = TT + 4;    // halo rows (pad 2 each side)
  constexpr int STR = 40;        // padded LDS stride (16B-aligned rows, no pow2 bank clash)
  __shared__ float xs[CIN * STR];
  const int b   = blockIdx.y;
  const int t0  = blockIdx.x * TT;
  const int tid = threadIdx.x;
  const float* xb = x + (size_t)b * T_ * CIN;
  for (int idx = tid; idx < JW * CIN; idx += 256) {
    int ci = idx % CIN;          // consecutive tid -> consecutive ci (coalesced)
    int j  = idx / CIN;
    int t  = t0 - 2 + j;
    xs[ci * STR + j] = (t >= 0 && t < T_) ? xb[(size_t)t * CIN + ci] : 0.f;
  }
  __syncthreads();
  const int co = tid;            // 256 threads = 256 output channels
  float acc[TT];
#pragma unroll
  for (int i = 0; i < TT; i++) acc[i] = 0.f;
  for (int ci = 0; ci < CIN; ci++) {
    float xv[JW];
    const float4* xp = (const float4*)&xs[ci * STR];
#pragma unroll
    for (int r = 0; r < JW / 4; r++) {
      float4 q = xp[r];
      xv[4*r+0] = q.x; xv[4*r+1] = q.y; xv[4*r+2] = q.z; xv[4*r+3] = q.w;
    }
#pragma unroll
    for (int k = 0; k < 5; k++) {
      float wv = w[((size_t)k * CIN + ci) * H_ + co];   // coalesced across co
#pragma unroll
      for (int i = 0; i < TT; i++) acc[i] = fmaf(xv[i + k], wv, acc[i]);
    }
  }
  const float bv = bias[co];
#pragma unroll
  for (int i = 0; i < TT; i++) {
    int t = t0 + i;
    if (t < T_) y[((size_t)b * T_ + t) * H_ + co] = tanhf(acc[i] + bv);
  }
}

// ---------------- W[b,t,s] = sum_h Wspec[b,t,h] * src_enc[b,s,h] --------
__global__ __launch_bounds__(256)
void einsum_ts(const float* __restrict__ A, const float* __restrict__ E,
               float* __restrict__ Wg)
{
  constexpr int GT = 128, GS = 64, KC = 16;
  __shared__ float As[KC][GT + 4];   // K-major (transposed) for vector reads
  __shared__ float Bs[KC][GS + 4];
  const int b   = blockIdx.z;
  const int t0  = blockIdx.x * GT;
  const int s0  = blockIdx.y * GS;
  const int tid = threadIdx.x;
  const int tx  = tid & 15;          // s micro index (4 cols)
  const int ty  = tid >> 4;          // t micro index (8 rows), 0..15
  float4 acc[8];
#pragma unroll
  for (int i = 0; i < 8; i++) acc[i] = make_float4(0.f, 0.f, 0.f, 0.f);
  const float* Ab = A + (size_t)b * T_ * H_;
  const float* Eb = E + (size_t)b * S_ * H_;
  for (int kc = 0; kc < H_; kc += KC) {
#pragma unroll
    for (int r = 0; r < 2; r++) {
      int f4  = tid + 256 * r;
      int row = f4 >> 2;             // 0..127
      int c4  = f4 & 3;
      int t   = t0 + row;
      float4 v = make_float4(0, 0, 0, 0);
      if (t < T_) v = *(const float4*)&Ab[(size_t)t * H_ + kc + c4 * 4];
      As[c4*4+0][row] = v.x; As[c4*4+1][row] = v.y;
      As[c4*4+2][row] = v.z; As[c4*4+3][row] = v.w;
    }
    {
      int row = tid >> 2;            // 0..63
      int c4  = tid & 3;
      int s   = s0 + row;
      float4 v = make_float4(0, 0, 0, 0);
      if (s < S_) v = *(const float4*)&Eb[(size_t)s * H_ + kc + c4 * 4];
      Bs[c4*4+0][row] = v.x; Bs[c4*4+1][row] = v.y;
      Bs[c4*4+2][row] = v.z; Bs[c4*4+3][row] = v.w;
    }
    __syncthreads();
#pragma unroll
    for (int kk = 0; kk < KC; kk++) {
      float4 a0 = *(const float4*)&As[kk][ty * 8];
      float4 a1 = *(const float4*)&As[kk][ty * 8 + 4];
      float4 bb = *(const float4*)&Bs[kk][tx * 4];
      float av[8] = {a0.x, a0.y, a0.z, a0.w, a1.x, a1.y, a1.z, a1.w};
#pragma unroll
      for (int i = 0; i < 8; i++) {
        acc[i].x = fmaf(av[i], bb.x, acc[i].x);
        acc[i].y = fmaf(av[i], bb.y, acc[i].y);
        acc[i].z = fmaf(av[i], bb.z, acc[i].z);
        acc[i].w = fmaf(av[i], bb.w, acc[i].w);
      }
    }
    __syncthreads();
  }
  float* Wb = Wg + (size_t)b * T_ * S_;
  const int s = s0 + tx * 4;
#pragma unroll
  for (int i = 0; i < 8; i++) {
    int t = t0 + ty * 8 + i;
    if (t < T_ && s < S_) *(float4*)&Wb[(size_t)t * S_ + s] = acc[i];
  }
}

// ---------------- per-(b,s) column softmax stats over T ------------------
// Writes M into mu[b][0][s], L into mu[b][1][s] (consumed then overwritten by dp).
__global__ __launch_bounds__(256)
void softmax_stats(const float* __restrict__ Wg, float* __restrict__ statsOut)
{
  const int b  = blockIdx.y;
  const int tx = threadIdx.x & 63;
  const int ty = threadIdx.x >> 6;            // 0..3
  const int s  = blockIdx.x * 64 + tx;
  const bool act = (s < S_);
  float m = -1e30f, l = 0.f;
  if (act) {
    const float* col = Wg + (size_t)b * T_ * S_ + s;
#pragma unroll 4
    for (int t = ty; t < T_; t += 4) {
      float v  = col[(size_t)t * S_];
      float nm = fmaxf(m, v);
      l = l * __expf(m - nm) + __expf(v - nm);
      m = nm;
    }
  }
  __shared__ float rm[4][64], rl[4][64];
  rm[ty][tx] = m; rl[ty][tx] = l;
  __syncthreads();
  if (ty == 0 && act) {
    float M = rm[0][tx];
#pragma unroll
    for (int q = 1; q < 4; q++) M = fmaxf(M, rm[q][tx]);
    float L = 0.f;
#pragma unroll
    for (int q = 0; q < 4; q++) L += rl[q][tx] * __expf(rm[q][tx] - M);
    float* st = statsOut + (size_t)b * T_ * S_;
    st[s]      = M;
    st[S_ + s] = L;
  }
}

// ---------------- monotonic-alignment Bayesian DP ------------------------
// One block per b. Computes alignments = softmax (in place over Wal) and the DP.
#define DP_STEP(I)                                                            \
  {                                                                           \
    const int t = t0 + (I);                                                   \
    if (t < T_) {                                                             \
      float av  = __expf(a_cur[I] - Mreg) * invL;  /* alignment (no mask) */  \
      float wdp = av * k_cur[I];                                              \
      float prev    = m;                                                      \
      float shifted = (act && s > 0) ? pb[(I) & 1][s - 1] : NEGV;             \
      float d    = prev - shifted;                                            \
      float e    = __expf(-fabsf(d));                                         \
      float hi   = fmaxf(prev, shifted);                                      \
      float mnew = wdp + hi + __logf(1.f + e);                                \
      float r    = 1.f / (1.f + e);                                           \
      float p0   = (d >= 0.f) ? r : 1.f - r;   /* prob of parent (t-1,s) */   \
      if (act) {                                                              \
        alb[t * S_ + s] = av;                                                 \
        mub[t * S_ + s] = mnew;                                               \
        pib[t * S_ + s] = make_float2(p0, 1.f - p0);                          \
        pb[((I) & 1) ^ 1][s] = mnew;                                          \
      }                                                                       \
      m = mnew;                                                               \
      __syncthreads();                                                        \
    }                                                                         \
  }

__global__ __launch_bounds__(448)
void dp_kernel(float* __restrict__ Wal,       // [B,T,S] raw scores in, alignments out
               const float* __restrict__ Mk,  // mask [B,T,S]
               float* __restrict__ muOut,     // [B,T,S]; rows 0/1 carry (M,L) stats on entry
               float2* __restrict__ piOut)    // [B,T,S,2]
{
  constexpr int PF = 8;
  __shared__ float pb[2][S_];
  const int b = blockIdx.x;
  const int s = threadIdx.x;
  const bool act = (s < S_);
  float*       alb = Wal   + (size_t)b * T_ * S_;
  const float* kb  = Mk    + (size_t)b * T_ * S_;
  float*       mub = muOut + (size_t)b * T_ * S_;
  float2*      pib = piOut + (size_t)b * T_ * S_;

  float Mreg = 0.f, invL = 1.f;
  if (act) { Mreg = mub[s]; invL = 1.f / mub[S_ + s]; }

  // t = 0
  float m = NEGV;
  if (act) {
    float av0 = __expf(alb[s] - Mreg) * invL;
    m = av0 * kb[s] + (s == 0 ? 0.f : NEGV);
    alb[s] = av0;
    mub[s] = m;
    pib[s] = make_float2(1.f, 0.f);
    pb[0][s] = m;
  }
  __syncthreads();

  float a_cur[PF], k_cur[PF];
#pragma unroll
  for (int i = 0; i < PF; i++) {
    int t = 1 + i;
    bool v = act && t < T_;
    a_cur[i] = v ? alb[t * S_ + s] : 0.f;
    k_cur[i] = v ? kb[t * S_ + s] : 0.f;
  }
  int t0 = 1;
  for (; t0 + PF <= T_; t0 += PF) {     // t0 stays odd -> parity (I&1) static
    float a_nxt[PF], k_nxt[PF];
#pragma unroll
    for (int i = 0; i < PF; i++) {
      int t = t0 + PF + i;
      bool v = act && t < T_;
      a_nxt[i] = v ? alb[t * S_ + s] : 0.f;
      k_nxt[i] = v ? kb[t * S_ + s] : 0.f;
    }
    DP_STEP(0) DP_STEP(1) DP_STEP(2) DP_STEP(3)
    DP_STEP(4) DP_STEP(5) DP_STEP(6) DP_STEP(7)
#pragma unroll
    for (int i = 0; i < PF; i++) { a_cur[i] = a_nxt[i]; k_cur[i] = k_nxt[i]; }
  }
  // tail (t0 = 1993, 7 valid steps)
  DP_STEP(0) DP_STEP(1) DP_STEP(2) DP_STEP(3)
  DP_STEP(4) DP_STEP(5) DP_STEP(6) DP_STEP(7)
}

// -------------------------------------------------------------------------
extern "C" void kernel_launch(void* const* d_in, const int* in_sizes, int n_in,
                              void* d_out, int out_size, void* d_ws, size_t ws_size,
                              hipStream_t stream)
{
  (void)in_sizes; (void)n_in; (void)out_size; (void)d_ws; (void)ws_size;
  const float* x   = (const float*)d_in[0];
  const float* enc = (const float*)d_in[1];
  const float* msk = (const float*)d_in[2];
  const float* w1  = (const float*)d_in[3];
  const float* b1  = (const float*)d_in[4];
  const float* w2  = (const float*)d_in[5];
  const float* b2  = (const float*)d_in[6];
  const float* w3  = (const float*)d_in[7];
  const float* b3  = (const float*)d_in[8];

  float* out = (float*)d_out;
  float* mu  = out;                       // [B,T,S]
  float* pi  = out + NMU;                 // [B,T,S,2]
  float* al  = out + NMU + NPI;           // [B,T,S]
  float* wsp = out + NMU + NPI + NMU;     // [B,T,H]
  float* h1  = pi;                        // scratch inside pi region (written last)
  float* h2  = pi + NWSP;

  dim3 cgrid((T_ + 31) / 32, B_);
  hipLaunchKernelGGL((conv1d_tanh<C0_>), cgrid, dim3(256), 0, stream, x,  w1, b1, h1);
  hipLaunchKernelGGL((conv1d_tanh<H_>),  cgrid, dim3(256), 0, stream, h1, w2, b2, h2);
  hipLaunchKernelGGL((conv1d_tanh<H_>),  cgrid, dim3(256), 0, stream, h2, w3, b3, wsp);
  hipLaunchKernelGGL(einsum_ts, dim3((T_ + 127) / 128, (S_ + 63) / 64, B_), dim3(256),
                     0, stream, wsp, enc, al);
  hipLaunchKernelGGL(softmax_stats, dim3((S_ + 63) / 64, B_), dim3(256), 0, stream, al, mu);
  hipLaunchKernelGGL(dp_kernel, dim3(B_), dim3(448), 0, stream, al, msk, mu, (float2*)pi);
}